// Round 8
// baseline (74.653 us; speedup 1.0000x reference)
//
#include <hip/hip_runtime.h>

#define NT 16384
#define D  2048
#define E  64
#define KCH 512           // K-chunk per wave (4 waves = full K)
#define TPC (KCH / 32)    // 16 k-tiles per chunk
#define NBLK (NT / 16)    // 1024 blocks, 16 tokens each

typedef _Float16 half8 __attribute__((ext_vector_type(8)));
typedef float f32x4 __attribute__((ext_vector_type(4)));

// ---- prep: W[k][e] fp32 -> W^T hi/lo panes in MFMA-fragment order ----
// pane offset(k,e) = (((kc*TPC + t)*4 + m)*16 + c)*32 + g*8 + j
// LDS-staged: coalesced float4 reads, coalesced half8 writes.
__global__ __launch_bounds__(256) void router_prep(const float* __restrict__ W,
                                                   _Float16* __restrict__ wthi,
                                                   _Float16* __restrict__ wtlo) {
    __shared__ _Float16 lhi[128][72];   // pad 72: row stride 144B -> banks shift 4/row
    __shared__ _Float16 llo[128][72];
    const int tid = threadIdx.x;
    const int k0  = blockIdx.x * 128;   // 16 blocks

    #pragma unroll
    for (int i = 0; i < 8; ++i) {
        const int fid = tid + i * 256;        // 0..2047
        const int kr  = fid >> 4;             // 0..127
        const int e4  = (fid & 15) << 2;
        const float4 v = *(const float4*)&W[(size_t)(k0 + kr) * E + e4];
        const float vv[4] = {v.x, v.y, v.z, v.w};
        #pragma unroll
        for (int j = 0; j < 4; ++j) {
            float hf = (float)(_Float16)vv[j];
            hf = (fabsf(hf) < 6.1035156e-5f) ? 0.f : hf;   // FTZ guard
            lhi[kr][e4 + j] = (_Float16)hf;
            llo[kr][e4 + j] = (_Float16)((vv[j] - hf) * 2048.f);
        }
    }
    __syncthreads();

    const int T = tid >> 6;          // 0..3 local t
    const int e = tid & 63;
    const int m = e >> 4, c = e & 15;
    const int kc  = k0 / KCH;
    const int t0l = (k0 % KCH) / 32;
    const size_t base = (((size_t)(kc * TPC + t0l + T) * 4 + m) * 16 + c) * 32;
    #pragma unroll
    for (int g = 0; g < 4; ++g) {
        half8 h, l;
        #pragma unroll
        for (int j = 0; j < 8; ++j) {
            h[j] = lhi[T * 32 + g * 8 + j][e];
            l[j] = llo[T * 32 + g * 8 + j][e];
        }
        *(half8*)&wthi[base + g * 8] = h;
        *(half8*)&wtlo[base + g * 8] = l;
    }
}

// ---- fused: GEMM (4 waves split K over 16 tokens) + LDS reduce + epilogue ----
__global__ __launch_bounds__(256, 4) void router_fused(const float* __restrict__ x,
                                                       const _Float16* __restrict__ wthi,
                                                       const _Float16* __restrict__ wtlo,
                                                       const float* __restrict__ bias,
                                                       float* __restrict__ out,
                                                       float* __restrict__ psum_part,
                                                       float* __restrict__ cnt_part) {
    __shared__ __align__(16) float red[4][16][68];  // [kc][c][e pad 68] = 17.4KB
    __shared__ float cnt[E];

    const int tid  = threadIdx.x;
    const int lane = tid & 63;
    const int w    = tid >> 6;     // wave = K-chunk 0..3
    const int g    = lane >> 4;
    const int c    = lane & 15;
    const int t0   = blockIdx.x * 16;

    const float*    xp  = &x[(size_t)(t0 + c) * D + w * KCH + g * 8];
    const _Float16* whp = &wthi[(size_t)w * TPC * 2048 + c * 32 + g * 8];
    const _Float16* wlp = &wtlo[(size_t)w * TPC * 2048 + c * 32 + g * 8];

    f32x4 am[4], ac[4];
    #pragma unroll
    for (int m = 0; m < 4; ++m) {
        am[m] = (f32x4){0.f, 0.f, 0.f, 0.f};
        ac[m] = (f32x4){0.f, 0.f, 0.f, 0.f};
    }

    float4 ca0 = *(const float4*)xp, ca1 = *(const float4*)(xp + 4);

    #pragma unroll 1
    for (int t = 0; t < TPC; ++t) {
        float4 na0, na1;
        if (t + 1 < TPC) {   // uniform scalar branch; prefetch next x tile
            na0 = *(const float4*)(xp + (t + 1) * 32);
            na1 = *(const float4*)(xp + (t + 1) * 32 + 4);
        }
        half8 bh, bl;
        {
            const float xv[8] = {ca0.x, ca0.y, ca0.z, ca0.w, ca1.x, ca1.y, ca1.z, ca1.w};
            #pragma unroll
            for (int j = 0; j < 8; ++j) {
                const float hf = (float)(_Float16)xv[j];
                bh[j] = (_Float16)hf;
                bl[j] = (_Float16)((xv[j] - hf) * 2048.f);
            }
        }
        #pragma unroll
        for (int m = 0; m < 4; ++m) {
            const half8 ah = *(const half8*)(whp + (size_t)(t * 4 + m) * 512);
            const half8 al = *(const half8*)(wlp + (size_t)(t * 4 + m) * 512);
            am[m] = __builtin_amdgcn_mfma_f32_16x16x32_f16(ah, bh, am[m], 0, 0, 0);
            ac[m] = __builtin_amdgcn_mfma_f32_16x16x32_f16(ah, bl, ac[m], 0, 0, 0);
            ac[m] = __builtin_amdgcn_mfma_f32_16x16x32_f16(al, bh, ac[m], 0, 0, 0);
        }
        ca0 = na0; ca1 = na1;
    }

    // partials -> LDS
    #pragma unroll
    for (int m = 0; m < 4; ++m) {
        f32x4 p;
        #pragma unroll
        for (int r = 0; r < 4; ++r) p[r] = am[m][r] + ac[m][r] * (1.f / 2048.f);
        *(f32x4*)&red[w][c][m * 16 + g * 4] = p;
    }
    __syncthreads();

    if (w == 0) {
        // wave 0: 16 tokens; lane(g,c) experts m*16+g*4+r for token t0+c
        cnt[lane] = 0.f;
        const int tok = t0 + c;
        float lg[4][4];
        #pragma unroll
        for (int m = 0; m < 4; ++m) {
            f32x4 s = *(const f32x4*)&red[0][c][m * 16 + g * 4];
            #pragma unroll
            for (int kc = 1; kc < 4; ++kc) {
                const f32x4 q = *(const f32x4*)&red[kc][c][m * 16 + g * 4];
                #pragma unroll
                for (int r = 0; r < 4; ++r) s[r] += q[r];
            }
            #pragma unroll
            for (int r = 0; r < 4; ++r) lg[m][r] = s[r] + bias[m * 16 + g * 4 + r];
        }

        // local top-2 over this lane's 16 experts
        float v1 = -3.4e38f, v2 = -3.4e38f; int i1 = 0, i2 = 0;
        #pragma unroll
        for (int m = 0; m < 4; ++m)
            #pragma unroll
            for (int r = 0; r < 4; ++r) {
                const float v = lg[m][r];
                const int   e = m * 16 + g * 4 + r;
                if (v > v1) { v2 = v1; i2 = i1; v1 = v; i1 = e; }
                else if (v > v2) { v2 = v; i2 = e; }
            }
        // merge across the 4 lanes (g) holding this token
        #pragma unroll
        for (int mask = 16; mask <= 32; mask <<= 1) {
            const float ov1 = __shfl_xor(v1, mask, 64); const int oi1 = __shfl_xor(i1, mask, 64);
            const float ov2 = __shfl_xor(v2, mask, 64); const int oi2 = __shfl_xor(i2, mask, 64);
            const bool oTop = (ov1 > v1) || (ov1 == v1 && oi1 < i1);
            if (oTop) {
                const bool k2 = (v1 > ov2) || (v1 == ov2 && i1 < oi2);
                v2 = k2 ? v1 : ov2; i2 = k2 ? i1 : oi2;
                v1 = ov1; i1 = oi1;
            } else {
                const bool k2 = (ov1 > v2) || (ov1 == v2 && oi1 < i2);
                v2 = k2 ? ov1 : v2; i2 = k2 ? oi1 : i2;
            }
        }

        // softmax (max = v1)
        float s = 0.f;
        #pragma unroll
        for (int m = 0; m < 4; ++m)
            #pragma unroll
            for (int r = 0; r < 4; ++r) { lg[m][r] = expf(lg[m][r] - v1); s += lg[m][r]; }
        s += __shfl_xor(s, 16, 64);
        s += __shfl_xor(s, 32, 64);
        const float inv = 1.f / s;

        // normalized probs -> per-expert sums across these 16 tokens
        #pragma unroll
        for (int m = 0; m < 4; ++m)
            #pragma unroll
            for (int r = 0; r < 4; ++r) {
                lg[m][r] *= inv;
                #pragma unroll
                for (int mask = 1; mask <= 8; mask <<= 1)
                    lg[m][r] += __shfl_xor(lg[m][r], mask, 64);
            }
        if (c == 0) {
            #pragma unroll
            for (int m = 0; m < 4; ++m)
                #pragma unroll
                for (int r = 0; r < 4; ++r)
                    psum_part[(size_t)blockIdx.x * E + m * 16 + g * 4 + r] = lg[m][r];
        }
        if (g == 0) {   // one leader lane per token
            const float p2 = expf(v2 - v1) * inv;
            out[tok * 2 + 0] = (float)i1;
            out[tok * 2 + 1] = (float)i2;
            out[2 * NT + tok * 2 + 0] = inv;     // p1 = exp(0)/s
            out[2 * NT + tok * 2 + 1] = p2;
            atomicAdd(&cnt[i1], 1.f);            // LDS, wave-0-local (lockstep-ordered)
            atomicAdd(&cnt[i2], 1.f);
        }
        cnt_part[(size_t)blockIdx.x * E + lane] = cnt[lane];
    }
}

// ---- aux: single block reduces psum_part||cnt_part (contiguous), computes loss ----
__global__ __launch_bounds__(1024) void router_aux(const float* __restrict__ parts,
                                                   float* __restrict__ out) {
    __shared__ float sp[E], sc[E];
    const int tid = threadIdx.x;
    // parts: [0, NBLK*E) = psum rows, [NBLK*E, 2*NBLK*E) = cnt rows; read as float4
    const f32x4* p4 = (const f32x4*)parts;
    f32x4 aP = {0.f, 0.f, 0.f, 0.f}, aC = {0.f, 0.f, 0.f, 0.f};
    #pragma unroll
    for (int i = 0; i < 32; ++i) {
        const f32x4 v = p4[tid + i * 1024];
        if (i < 16) { aP[0] += v[0]; aP[1] += v[1]; aP[2] += v[2]; aP[3] += v[3]; }
        else        { aC[0] += v[0]; aC[1] += v[1]; aC[2] += v[2]; aC[3] += v[3]; }
    }
    if (tid < 128) { if (tid < E) sp[tid] = 0.f; else sc[tid - E] = 0.f; }
    __syncthreads();
    const int e0 = (tid & 15) * 4;
    #pragma unroll
    for (int r = 0; r < 4; ++r) {
        atomicAdd(&sp[e0 + r], aP[r]);
        atomicAdd(&sc[e0 + r], aC[r]);
    }
    __syncthreads();
    if (tid < E) {
        float v = sp[tid] * sc[tid] * (1.0f / NT) * (1.0f / NT);
        #pragma unroll
        for (int off = 32; off > 0; off >>= 1) v += __shfl_down(v, off);
        if (tid == 0) out[NT * 2 * 2] = (float)E * v;
    }
}

extern "C" void kernel_launch(void* const* d_in, const int* in_sizes, int n_in,
                              void* d_out, int out_size, void* d_ws, size_t ws_size,
                              hipStream_t stream) {
    const float* x = (const float*)d_in[0];
    const float* W = (const float*)d_in[1];
    const float* b = (const float*)d_in[2];
    float* out = (float*)d_out;

    // ws: | wthi 256KB | wtlo 256KB | psum_part 256KB | cnt_part 256KB |
    char* base = (char*)d_ws;
    _Float16* wthi = (_Float16*)base;
    _Float16* wtlo = wthi + (size_t)D * E;
    float* psum_part = (float*)(base + 2 * (size_t)D * E * sizeof(_Float16));
    float* cnt_part  = psum_part + (size_t)NBLK * E;

    router_prep<<<dim3(D / 128), dim3(256), 0, stream>>>(W, wthi, wtlo);
    router_fused<<<dim3(NBLK), dim3(256), 0, stream>>>(x, wthi, wtlo, b, out,
                                                       psum_part, cnt_part);
    router_aux<<<dim3(1), dim3(1024), 0, stream>>>(psum_part, out);
}

// Round 9
// 63.401 us; speedup vs baseline: 1.1775x; 1.1775x over previous
//
#include <hip/hip_runtime.h>

#define NT 16384
#define D  2048
#define E  64
#define KCH 256           // K-chunk per wave (8 waves = full K)
#define TPC (KCH / 32)    // 8 k-tiles per chunk
#define NBLK (NT / 32)    // 512 blocks, 32 tokens each

typedef _Float16 half8 __attribute__((ext_vector_type(8)));
typedef float f32x4 __attribute__((ext_vector_type(4)));

// ---- prep: W[k][e] fp32 -> W^T hi/lo panes in MFMA-fragment order ----
// pane offset(k,e) = (((kc*TPC + t)*4 + m)*16 + c)*32 + g*8 + j
__global__ __launch_bounds__(256) void router_prep(const float* __restrict__ W,
                                                   _Float16* __restrict__ wthi,
                                                   _Float16* __restrict__ wtlo) {
    const int id  = blockIdx.x * 256 + threadIdx.x;  // 0..32767, grid 128
    const int k   = id >> 4;
    const int e4  = (id & 15) << 2;
    const int kc  = k / KCH;
    const int kr  = k % KCH;
    const int t   = kr >> 5;
    const int g   = (kr >> 3) & 3;
    const int j   = kr & 7;
    const float4 v = *(const float4*)&W[(size_t)k * E + e4];
    const float vv[4] = {v.x, v.y, v.z, v.w};
    #pragma unroll
    for (int i = 0; i < 4; ++i) {
        const int e = e4 + i;
        const int m = e >> 4, c = e & 15;
        const size_t off = ((((size_t)(kc * TPC + t) * 4 + m) * 16 + c) * 32) + g * 8 + j;
        float hf = (float)(_Float16)vv[i];
        hf = (fabsf(hf) < 6.1035156e-5f) ? 0.f : hf;   // FTZ guard
        wthi[off] = (_Float16)hf;
        wtlo[off] = (_Float16)((vv[i] - hf) * 2048.f);
    }
}

// ---- fused: GEMM (8 waves split K over 32 tokens) + 2-stage LDS reduce + epilogue ----
__global__ __launch_bounds__(512, 4) void router_fused(const float* __restrict__ x,
                                                       const _Float16* __restrict__ wthi,
                                                       const _Float16* __restrict__ wtlo,
                                                       const float* __restrict__ bias,
                                                       float* __restrict__ out,
                                                       float* __restrict__ psum_part,
                                                       float* __restrict__ cnt_part) {
    __shared__ __align__(16) float red[4][2][16][68];  // [pane][tt][c][e pad 68] = 34.8KB
    __shared__ float cnt[E];

    const int tid  = threadIdx.x;
    const int lane = tid & 63;
    const int w    = tid >> 6;     // wave = K-chunk 0..7
    const int g    = lane >> 4;
    const int c    = lane & 15;
    const int t0   = blockIdx.x * 32;

    if (tid < E) cnt[tid] = 0.f;

    const float*    xp0 = &x[(size_t)(t0 + c) * D + w * KCH + g * 8];
    const float*    xp1 = &x[(size_t)(t0 + 16 + c) * D + w * KCH + g * 8];
    const _Float16* whp = &wthi[(size_t)w * TPC * 2048 + c * 32 + g * 8];
    const _Float16* wlp = &wtlo[(size_t)w * TPC * 2048 + c * 32 + g * 8];

    f32x4 am[2][4], ac[2][4];
    #pragma unroll
    for (int tt = 0; tt < 2; ++tt)
        #pragma unroll
        for (int m = 0; m < 4; ++m) {
            am[tt][m] = (f32x4){0.f, 0.f, 0.f, 0.f};
            ac[tt][m] = (f32x4){0.f, 0.f, 0.f, 0.f};
        }

    float4 ca0 = *(const float4*)xp0, ca1 = *(const float4*)(xp0 + 4);
    float4 cb0 = *(const float4*)xp1, cb1 = *(const float4*)(xp1 + 4);

    #pragma unroll 1
    for (int t = 0; t < TPC; ++t) {
        float4 na0, na1, nb0, nb1;
        if (t + 1 < TPC) {   // uniform scalar branch; prefetch next x tile
            na0 = *(const float4*)(xp0 + (t + 1) * 32);
            na1 = *(const float4*)(xp0 + (t + 1) * 32 + 4);
            nb0 = *(const float4*)(xp1 + (t + 1) * 32);
            nb1 = *(const float4*)(xp1 + (t + 1) * 32 + 4);
        }
        half8 bh0, bl0, bh1, bl1;
        {
            const float xv0[8] = {ca0.x, ca0.y, ca0.z, ca0.w, ca1.x, ca1.y, ca1.z, ca1.w};
            const float xv1[8] = {cb0.x, cb0.y, cb0.z, cb0.w, cb1.x, cb1.y, cb1.z, cb1.w};
            #pragma unroll
            for (int j = 0; j < 8; ++j) {
                float h0 = (float)(_Float16)xv0[j];
                bh0[j] = (_Float16)h0;  bl0[j] = (_Float16)((xv0[j] - h0) * 2048.f);
                float h1 = (float)(_Float16)xv1[j];
                bh1[j] = (_Float16)h1;  bl1[j] = (_Float16)((xv1[j] - h1) * 2048.f);
            }
        }
        #pragma unroll
        for (int m = 0; m < 4; ++m) {
            const half8 ah = *(const half8*)(whp + (size_t)(t * 4 + m) * 512);
            const half8 al = *(const half8*)(wlp + (size_t)(t * 4 + m) * 512);
            am[0][m] = __builtin_amdgcn_mfma_f32_16x16x32_f16(ah, bh0, am[0][m], 0, 0, 0);
            ac[0][m] = __builtin_amdgcn_mfma_f32_16x16x32_f16(ah, bl0, ac[0][m], 0, 0, 0);
            ac[0][m] = __builtin_amdgcn_mfma_f32_16x16x32_f16(al, bh0, ac[0][m], 0, 0, 0);
            am[1][m] = __builtin_amdgcn_mfma_f32_16x16x32_f16(ah, bh1, am[1][m], 0, 0, 0);
            ac[1][m] = __builtin_amdgcn_mfma_f32_16x16x32_f16(ah, bl1, ac[1][m], 0, 0, 0);
            ac[1][m] = __builtin_amdgcn_mfma_f32_16x16x32_f16(al, bh1, ac[1][m], 0, 0, 0);
        }
        ca0 = na0; ca1 = na1; cb0 = nb0; cb1 = nb1;
    }

    // combine hi/lo into per-wave partials
    float pp[2][4][4];
    #pragma unroll
    for (int tt = 0; tt < 2; ++tt)
        #pragma unroll
        for (int m = 0; m < 4; ++m)
            #pragma unroll
            for (int r = 0; r < 4; ++r)
                pp[tt][m][r] = am[tt][m][r] + ac[tt][m][r] * (1.f / 2048.f);

    // stage 1: waves 4..7 write panes
    if (w >= 4) {
        #pragma unroll
        for (int tt = 0; tt < 2; ++tt)
            #pragma unroll
            for (int m = 0; m < 4; ++m)
                *(f32x4*)&red[w - 4][tt][c][m * 16 + g * 4] =
                    (f32x4){pp[tt][m][0], pp[tt][m][1], pp[tt][m][2], pp[tt][m][3]};
    }
    __syncthreads();
    // stage 2: waves 0..3 add pane + own partial, write back
    if (w < 4) {
        #pragma unroll
        for (int tt = 0; tt < 2; ++tt)
            #pragma unroll
            for (int m = 0; m < 4; ++m) {
                f32x4 q = *(const f32x4*)&red[w][tt][c][m * 16 + g * 4];
                #pragma unroll
                for (int r = 0; r < 4; ++r) q[r] += pp[tt][m][r];
                *(f32x4*)&red[w][tt][c][m * 16 + g * 4] = q;
            }
    }
    __syncthreads();

    if (w < 2) {
        // wave w: tokens t0 + w*16 + c; lane(g,c) experts m*16+g*4+r
        const int tok = t0 + w * 16 + c;
        float lg[4][4];
        #pragma unroll
        for (int m = 0; m < 4; ++m) {
            f32x4 s = *(const f32x4*)&red[0][w][c][m * 16 + g * 4];
            #pragma unroll
            for (int kc = 1; kc < 4; ++kc) {
                const f32x4 q = *(const f32x4*)&red[kc][w][c][m * 16 + g * 4];
                #pragma unroll
                for (int r = 0; r < 4; ++r) s[r] += q[r];
            }
            #pragma unroll
            for (int r = 0; r < 4; ++r) lg[m][r] = s[r] + bias[m * 16 + g * 4 + r];
        }

        // local top-2 over this lane's 16 experts
        float v1 = -3.4e38f, v2 = -3.4e38f; int i1 = 0, i2 = 0;
        #pragma unroll
        for (int m = 0; m < 4; ++m)
            #pragma unroll
            for (int r = 0; r < 4; ++r) {
                const float v = lg[m][r];
                const int   e = m * 16 + g * 4 + r;
                if (v > v1) { v2 = v1; i2 = i1; v1 = v; i1 = e; }
                else if (v > v2) { v2 = v; i2 = e; }
            }
        // merge across the 4 lanes (g) holding this token
        #pragma unroll
        for (int mask = 16; mask <= 32; mask <<= 1) {
            const float ov1 = __shfl_xor(v1, mask, 64); const int oi1 = __shfl_xor(i1, mask, 64);
            const float ov2 = __shfl_xor(v2, mask, 64); const int oi2 = __shfl_xor(i2, mask, 64);
            const bool oTop = (ov1 > v1) || (ov1 == v1 && oi1 < i1);
            if (oTop) {
                const bool k2 = (v1 > ov2) || (v1 == ov2 && i1 < oi2);
                v2 = k2 ? v1 : ov2; i2 = k2 ? i1 : oi2;
                v1 = ov1; i1 = oi1;
            } else {
                const bool k2 = (ov1 > v2) || (ov1 == v2 && oi1 < i2);
                v2 = k2 ? ov1 : v2; i2 = k2 ? oi1 : i2;
            }
        }

        // softmax (max = v1)
        float s = 0.f;
        #pragma unroll
        for (int m = 0; m < 4; ++m)
            #pragma unroll
            for (int r = 0; r < 4; ++r) { lg[m][r] = expf(lg[m][r] - v1); s += lg[m][r]; }
        s += __shfl_xor(s, 16, 64);
        s += __shfl_xor(s, 32, 64);
        const float inv = 1.f / s;

        // normalized probs -> per-expert sums across this wave's 16 tokens
        #pragma unroll
        for (int m = 0; m < 4; ++m)
            #pragma unroll
            for (int r = 0; r < 4; ++r) {
                lg[m][r] *= inv;
                #pragma unroll
                for (int mask = 1; mask <= 8; mask <<= 1)
                    lg[m][r] += __shfl_xor(lg[m][r], mask, 64);
            }
        if (c == 0) {
            const int row = blockIdx.x * 2 + w;
            #pragma unroll
            for (int m = 0; m < 4; ++m)
                #pragma unroll
                for (int r = 0; r < 4; ++r)
                    psum_part[(size_t)row * E + m * 16 + g * 4 + r] = lg[m][r];
        }
        if (g == 0) {   // one leader lane per token
            const float p2 = expf(v2 - v1) * inv;
            out[tok * 2 + 0] = (float)i1;
            out[tok * 2 + 1] = (float)i2;
            out[2 * NT + tok * 2 + 0] = inv;     // p1 = exp(0)/s
            out[2 * NT + tok * 2 + 1] = p2;
            atomicAdd(&cnt[i1], 1.f);            // LDS atomic
            atomicAdd(&cnt[i2], 1.f);
        }
    }
    __syncthreads();
    if (tid < E) cnt_part[(size_t)blockIdx.x * E + tid] = cnt[tid];
}

// ---- aux: single block reduces psum(1024 rows) || cnt(512 rows), computes loss ----
__global__ __launch_bounds__(1024) void router_aux(const float* __restrict__ parts,
                                                   float* __restrict__ out) {
    __shared__ float sp[E], sc[E];
    const int tid = threadIdx.x;
    // parts: [0, 2*NBLK*E) psum rows, then [.., 3*NBLK*E) cnt rows; total 24576 float4
    const f32x4* p4 = (const f32x4*)parts;
    f32x4 aP = {0.f, 0.f, 0.f, 0.f}, aC = {0.f, 0.f, 0.f, 0.f};
    #pragma unroll
    for (int i = 0; i < 24; ++i) {
        const f32x4 v = p4[tid + i * 1024];
        if (i < 16) { aP[0] += v[0]; aP[1] += v[1]; aP[2] += v[2]; aP[3] += v[3]; }
        else        { aC[0] += v[0]; aC[1] += v[1]; aC[2] += v[2]; aC[3] += v[3]; }
    }
    if (tid < 128) { if (tid < E) sp[tid] = 0.f; else sc[tid - E] = 0.f; }
    __syncthreads();
    const int e0 = (tid & 15) * 4;
    #pragma unroll
    for (int r = 0; r < 4; ++r) {
        atomicAdd(&sp[e0 + r], aP[r]);
        atomicAdd(&sc[e0 + r], aC[r]);
    }
    __syncthreads();
    if (tid < E) {
        float v = sp[tid] * sc[tid] * (1.0f / NT) * (1.0f / NT);
        #pragma unroll
        for (int off = 32; off > 0; off >>= 1) v += __shfl_down(v, off);
        if (tid == 0) out[NT * 2 * 2] = (float)E * v;
    }
}

extern "C" void kernel_launch(void* const* d_in, const int* in_sizes, int n_in,
                              void* d_out, int out_size, void* d_ws, size_t ws_size,
                              hipStream_t stream) {
    const float* x = (const float*)d_in[0];
    const float* W = (const float*)d_in[1];
    const float* b = (const float*)d_in[2];
    float* out = (float*)d_out;

    // ws: | wthi 256KB | wtlo 256KB | psum_part 256KB | cnt_part 128KB |
    char* base = (char*)d_ws;
    _Float16* wthi = (_Float16*)base;
    _Float16* wtlo = wthi + (size_t)D * E;
    float* psum_part = (float*)(base + 2 * (size_t)D * E * sizeof(_Float16));
    float* cnt_part  = psum_part + (size_t)2 * NBLK * E;

    router_prep<<<dim3(128), dim3(256), 0, stream>>>(W, wthi, wtlo);
    router_fused<<<dim3(NBLK), dim3(512), 0, stream>>>(x, wthi, wtlo, b, out,
                                                       psum_part, cnt_part);
    router_aux<<<dim3(1), dim3(1024), 0, stream>>>(psum_part, out);
}